// Round 3
// baseline (16.109 us; speedup 1.0000x reference)
//
#include <hip/hip_runtime.h>

#define B_DIM 2048
#define F_DIM 512
#define U_DIM 256

constexpr float K_L2E = 21.64042561333445f;   // 15 * log2(e)
constexpr float INV_K = 1.0f / K_L2E;

using short8 = __attribute__((ext_vector_type(8))) short;  // 8 bf16 = 4 VGPRs
using f32x4  = __attribute__((ext_vector_type(4))) float;

__device__ __forceinline__ unsigned short f2bf(float f) {
    unsigned u = __float_as_uint(f);
    return (unsigned short)((u + 0x7FFFu + ((u >> 16) & 1u)) >> 16);  // RNE, finite inputs
}

// EA frag layout: chunk ((m*128 + rt)*16 + kb)*64 + lane; lane = (b%16) + 16*g,
//   short8 holds k = 8*g + i  (f = 32*kb + 8*g + i)
// EW frag layout: chunk (ut*16 + kb)*64 + lane; lane = (u%16) + 16*g, same k mapping.
__global__ __launch_bounds__(256)
void prep_k(const float* __restrict__ x, const float* __restrict__ w,
            float* __restrict__ mx, float* __restrict__ mn,
            unsigned short* __restrict__ ea, unsigned short* __restrict__ ew) {
    const int tid  = threadIdx.x;
    const int wv   = tid >> 6;
    const int lane = tid & 63;
    const int b    = (blockIdx.x << 2) + wv;   // 4 rows per block, one per wave

    // lane holds f = 8*lane .. 8*lane+7
    const float4* xr = reinterpret_cast<const float4*>(x + b * F_DIM);
    float4 v0 = xr[lane * 2];
    float4 v1 = xr[lane * 2 + 1];
    float f8[8] = {v0.x, v0.y, v0.z, v0.w, v1.x, v1.y, v1.z, v1.w};
    float hi = f8[0], lo = f8[0];
#pragma unroll
    for (int i = 1; i < 8; ++i) { hi = fmaxf(hi, f8[i]); lo = fminf(lo, f8[i]); }
#pragma unroll
    for (int off = 32; off; off >>= 1) {
        hi = fmaxf(hi, __shfl_xor(hi, off));
        lo = fminf(lo, __shfl_xor(lo, off));
    }
    if (lane == 0) { mx[b] = hi; mn[b] = lo; }

    const int rt = b >> 4, br = b & 15;
    const int kb = lane >> 2, g = lane & 3;    // f = 8*lane = 32*kb + 8*g
    const int chunk_lane = br + (g << 4);
    {   // mode 0 (softmax side): exp2(K*(x - max)) <= 1
        short8 c;
#pragma unroll
        for (int i = 0; i < 8; ++i) c[i] = (short)f2bf(exp2f(K_L2E * (f8[i] - hi)));
        reinterpret_cast<short8*>(ea)[(rt * 16 + kb) * 64 + chunk_lane] = c;
    }
    {   // mode 1 (softmin side): exp2(K*(min - x)) <= 1
        short8 c;
#pragma unroll
        for (int i = 0; i < 8; ++i) c[i] = (short)f2bf(exp2f(K_L2E * (lo - f8[i])));
        reinterpret_cast<short8*>(ea)[((128 + rt) * 16 + kb) * 64 + chunk_lane] = c;
    }

    // B-operand transform: one thread per B-frag chunk, coalesced 16B stores.
    if (blockIdx.x < 64) {
        const int c    = (blockIdx.x << 8) + tid;     // chunk id in [0, 16384)
        const int cl   = c & 63;                      // chunk lane
        const int ckb  = (c >> 6) & 15;
        const int cut  = c >> 10;                     // u tile 0..15
        const int u    = (cut << 4) + (cl & 15);
        const int gw   = cl >> 4;
        const int fb   = (ckb << 5) + (gw << 3);      // f base for this short8
        const float s  = (u < 128) ? K_L2E : -K_L2E;
        short8 cc;
#pragma unroll
        for (int i = 0; i < 8; ++i)
            cc[i] = (short)f2bf(exp2f(s * w[(fb + i) * U_DIM + u]));
        reinterpret_cast<short8*>(ew)[c] = cc;
    }
}

// ---------------- kernel 2: MFMA GEMM, 2rt x 2ut per wave, no LDS -----------
__global__ __launch_bounds__(128)
void mfma_k(const unsigned short* __restrict__ ea, const unsigned short* __restrict__ ew,
            const float* __restrict__ mx, const float* __restrict__ mn,
            float* __restrict__ out) {
    const int wv   = threadIdx.x >> 6;
    const int lane = threadIdx.x & 63;
    const int gid  = (blockIdx.x << 1) + wv;   // 512 waves
    const int rtp  = gid >> 3;                 // 64 row-tile pairs
    const int utp  = gid & 7;                  // 8 u-tile pairs
    const int rt0  = rtp << 1;
    const int ut0  = utp << 1;
    const int m    = (utp >= 4);               // mode uniform per wave

    const short8* A0 = reinterpret_cast<const short8*>(ea) + ((m * 128 + rt0) * 16) * 64 + lane;
    const short8* A1 = A0 + 16 * 64;
    const short8* B0 = reinterpret_cast<const short8*>(ew) + (ut0 * 16) * 64 + lane;
    const short8* B1 = B0 + 16 * 64;

    f32x4 acc00 = {0.f,0.f,0.f,0.f}, acc01 = {0.f,0.f,0.f,0.f};
    f32x4 acc10 = {0.f,0.f,0.f,0.f}, acc11 = {0.f,0.f,0.f,0.f};
#pragma unroll
    for (int kb = 0; kb < 16; ++kb) {
        short8 a0 = A0[kb * 64];
        short8 a1 = A1[kb * 64];
        short8 b0 = B0[kb * 64];
        short8 b1 = B1[kb * 64];
        acc00 = __builtin_amdgcn_mfma_f32_16x16x32_bf16(a0, b0, acc00, 0, 0, 0);
        acc01 = __builtin_amdgcn_mfma_f32_16x16x32_bf16(a0, b1, acc01, 0, 0, 0);
        acc10 = __builtin_amdgcn_mfma_f32_16x16x32_bf16(a1, b0, acc10, 0, 0, 0);
        acc11 = __builtin_amdgcn_mfma_f32_16x16x32_bf16(a1, b1, acc11, 0, 0, 0);
    }

    // C/D layout: col = lane&15, row = (lane>>4)*4 + r
    const int j    = lane & 15;
    const int quad = lane >> 4;
    const float* st = m ? mn : mx;

#pragma unroll
    for (int ri = 0; ri < 2; ++ri) {
        const int brow = (rt0 + ri) * 16 + (quad << 2);
#pragma unroll
        for (int r = 0; r < 4; ++r) {
            float sv = st[brow + r];
            {
                f32x4 a = ri ? acc10 : acc00;
                float lg = __log2f(a[r]) * INV_K;
                out[(brow + r) * U_DIM + (ut0 << 4) + j] = m ? (sv - lg) : (sv + lg);
            }
            {
                f32x4 a = ri ? acc11 : acc01;
                float lg = __log2f(a[r]) * INV_K;
                out[(brow + r) * U_DIM + ((ut0 + 1) << 4) + j] = m ? (sv - lg) : (sv + lg);
            }
        }
    }
}

extern "C" void kernel_launch(void* const* d_in, const int* in_sizes, int n_in,
                              void* d_out, int out_size, void* d_ws, size_t ws_size,
                              hipStream_t stream) {
    const float* x = (const float*)d_in[0];
    const float* w = (const float*)d_in[1];
    float* out = (float*)d_out;
    float* mx = (float*)d_ws;                              // 2048 f32
    float* mn = mx + B_DIM;                                // 2048 f32
    unsigned short* ea = (unsigned short*)((char*)d_ws + 16384);   // 4 MB
    unsigned short* ew = ea + 2 * 128 * 16 * 64 * 8;               // 256 KB

    prep_k<<<512, 256, 0, stream>>>(x, w, mx, mn, ea, ew);
    mfma_k<<<256, 128, 0, stream>>>(ea, ew, mx, mn, out);
}

// Round 4
// 14.961 us; speedup vs baseline: 1.0767x; 1.0767x over previous
//
#include <hip/hip_runtime.h>

#define B_DIM 2048
#define F_DIM 512
#define U_DIM 256

constexpr float K_L2E = 21.64042561333445f;   // 15 * log2(e)
constexpr float INV_K = 1.0f / K_L2E;

using short8 = __attribute__((ext_vector_type(8))) short;  // 8 bf16 = 4 VGPRs
using f32x4  = __attribute__((ext_vector_type(4))) float;

__device__ __forceinline__ unsigned short f2bf(float f) {
    unsigned u = __float_as_uint(f);
    return (unsigned short)((u + 0x7FFFu + ((u >> 16) & 1u)) >> 16);  // RNE, finite inputs
}

// ---------------- kernel 1: w -> exp'd B fragments (256 KB, produced once) ----------------
// EW frag layout: chunk (ut*16 + kb)*64 + cl; cl = (u%16) + 16*g, short8 elem i -> f = 32*kb+8*g+i
__global__ __launch_bounds__(256)
void prep_w(const float* __restrict__ w, unsigned short* __restrict__ ew) {
    const int c   = (blockIdx.x << 8) + threadIdx.x;   // chunk id in [0, 16384)
    const int cl  = c & 63;
    const int ckb = (c >> 6) & 15;
    const int cut = c >> 10;
    const int u   = (cut << 4) + (cl & 15);
    const int gw  = cl >> 4;
    const int fb  = (ckb << 5) + (gw << 3);
    const float s = (u < 128) ? K_L2E : -K_L2E;
    short8 cc;
#pragma unroll
    for (int i = 0; i < 8; ++i)
        cc[i] = (short)f2bf(exp2f(s * w[(fb + i) * U_DIM + u]));
    reinterpret_cast<short8*>(ew)[c] = cc;
}

// ---------------- kernel 2: fused rowstat + exp + MFMA + log -----------------------------
// block = (rt, utq): 16 output rows x 64 units, 4 waves, one 16x16 tile per wave.
__global__ __launch_bounds__(256)
void fused_k(const float* __restrict__ x, const unsigned short* __restrict__ ew,
             float* __restrict__ out) {
    __shared__ short8 sA[1024];     // 16 chunks x 64 slots x 16B = 16 KB, XOR-swizzled
    __shared__ float  sst[16];

    const int tid  = threadIdx.x;
    const int wv   = tid >> 6;
    const int lane = tid & 63;
    const int rt   = blockIdx.x >> 2;       // 128 row tiles
    const int utq  = blockIdx.x & 3;
    const int mode = utq >> 1;              // uts 0..7 -> softmax, 8..15 -> softmin
    const int ut   = (utq << 2) + wv;

    // ---- stage A: load x rows, row-reduce, exp2, write swizzled LDS frags ----
    const int   kb_w = lane >> 2;           // chunk this lane's f-range belongs to
    const int   g_w  = lane & 3;
    const float sgn  = mode ? -1.f : 1.f;   // t = sgn*x; max(t) handles both modes

#pragma unroll
    for (int j = 0; j < 4; ++j) {
        const int row = (wv << 2) + j;      // 4 rows per wave -> 16 rows per block
        const float4* xr = reinterpret_cast<const float4*>(x + (rt * 16 + row) * F_DIM);
        float4 v0 = xr[lane * 2];
        float4 v1 = xr[lane * 2 + 1];
        float t[8] = {sgn * v0.x, sgn * v0.y, sgn * v0.z, sgn * v0.w,
                      sgn * v1.x, sgn * v1.y, sgn * v1.z, sgn * v1.w};
        float hi = t[0];
#pragma unroll
        for (int i = 1; i < 8; ++i) hi = fmaxf(hi, t[i]);
#pragma unroll
        for (int off = 32; off; off >>= 1) hi = fmaxf(hi, __shfl_xor(hi, off));
        if (lane == 0) sst[row] = hi;
        short8 cb;
#pragma unroll
        for (int i = 0; i < 8; ++i) cb[i] = (short)f2bf(exp2f(K_L2E * (t[i] - hi)));
        // logical slot p = row + 16*g within chunk kb; XOR-swizzle low bits for bank spread
        sA[(kb_w << 6) + ((row + (g_w << 4)) ^ (kb_w & 7))] = cb;
    }
    __syncthreads();

    // ---- MFMA loop: A from LDS (conflict-free swizzled), B from L2-hot EW ----
    const short8* B = reinterpret_cast<const short8*>(ew) + (ut << 4) * 64 + lane;
    f32x4 acc = {0.f, 0.f, 0.f, 0.f};
#pragma unroll
    for (int kb = 0; kb < 16; ++kb) {
        short8 a = sA[(kb << 6) + (lane ^ (kb & 7))];
        acc = __builtin_amdgcn_mfma_f32_16x16x32_bf16(a, B[kb * 64], acc, 0, 0, 0);
    }

    // ---- epilogue: C/D layout col = lane&15, row = (lane>>4)*4 + r ----
    const int j    = lane & 15;
    const int quad = lane >> 4;
#pragma unroll
    for (int r = 0; r < 4; ++r) {
        const int row = (quad << 2) + r;
        float res = sst[row] + __log2f(acc[r]) * INV_K;
        out[(rt * 16 + row) * U_DIM + (ut << 4) + j] = mode ? -res : res;
    }
}

extern "C" void kernel_launch(void* const* d_in, const int* in_sizes, int n_in,
                              void* d_out, int out_size, void* d_ws, size_t ws_size,
                              hipStream_t stream) {
    const float* x = (const float*)d_in[0];
    const float* w = (const float*)d_in[1];
    float* out = (float*)d_out;
    unsigned short* ew = (unsigned short*)d_ws;   // 16*16*64*8 bf16 = 256 KB

    prep_w<<<64, 256, 0, stream>>>(w, ew);
    fused_k<<<512, 256, 0, stream>>>(x, ew, out);
}